// Round 17
// baseline (92.035 us; speedup 1.0000x reference)
//
#include <hip/hip_runtime.h>

// ---------------------------------------------------------------------------
// StickyHDPHMMVI emission log-likelihood, f16 MFMA + symmetry formulation:
// out[bt,k] = c0_k - 0.5 * sum_x A[bt,x] * B[k,x]
// x enumerates SYMMETRIC pair-blocks (bI<=bJ) of the 64x64 (d,e) space:
//   pair pb=(bI,bJ), chunks c = pb*2+p (p=0,1), slot s = g*8+q:
//     d = bI*8 + p*4 + g, e = bJ*8 + q
//     A = S0[d][e] (mu muT + F FT),  B = E_k[d][e] * (bI<bJ ? 2 : 1)
//   c=72,73: A = mu[t],  B = -2*v_k[t];  c=74,75: A = var[t], B = E_k[t,t]
// B lane-ordered: BG[((c*3 + j)*64 + kc*4 + g)*8 + q], k = j*16+kc
// r17: B comes to the MFMA through a per-group 2-slot LDS ring, staged by a
// producer wave with issue-early/write-late reg staging (T14), one chunk per
// block-wide barrier round. 8 waves = 4 chunk-groups (wp) x 2 bt-tiles (wt);
// consumer B path is pure ds_read_b128. Rounds t=0..18: chunk 18wp+t, t=18 ->
// ext chunk 72+wp. Ext A-fragment hoisted out of the loop. BUILD operands via
// bit_cast h2 structs. Prior refuted theories: addressing(r13), reg budget
// (r15), forced occupancy (r11: spill storm at (256,8)), L1 pairing (r16).
// ---------------------------------------------------------------------------

#define BT_TOTAL 32768
#define BT_BLK 32
#define NCHUNK 76

typedef _Float16 f16;
typedef __attribute__((ext_vector_type(8))) _Float16 f16x8;
typedef __attribute__((ext_vector_type(4))) _Float16 f16x4;
typedef __attribute__((ext_vector_type(2))) _Float16 h2;
typedef __attribute__((ext_vector_type(4))) float f32x4;
typedef struct { h2 p[4]; } h2q;

#if __has_builtin(__builtin_amdgcn_fdot2)
#define DOT2(a, b, c) __builtin_amdgcn_fdot2((a), (b), (c), false)
#else
#define DOT2(a, b, c) fmaf((float)(a)[0], (float)(b)[0], fmaf((float)(a)[1], (float)(b)[1], (c)))
#endif

// pair-block tables (bJ outer 0..7, bI inner 0..bJ)
__constant__ unsigned char PB_BJ[36] =
  {0, 1,1, 2,2,2, 3,3,3,3, 4,4,4,4,4, 5,5,5,5,5,5, 6,6,6,6,6,6,6, 7,7,7,7,7,7,7,7};
__constant__ unsigned char PB_BI[36] =
  {0, 0,1, 0,1,2, 0,1,2,3, 0,1,2,3,4, 0,1,2,3,4,5, 0,1,2,3,4,5,6, 0,1,2,3,4,5,6,7};

__device__ __forceinline__ float digammaf_(float x){
  float r = 0.f;
  while (x < 6.f){ r -= 1.f / x; x += 1.f; }
  float xi = 1.f / x;
  float xi2 = xi * xi;
  return r + logf(x) - 0.5f * xi
         - xi2 * (0.083333333333f - xi2 * (0.0083333333333f - xi2 * 0.0039682539683f));
}

__device__ __forceinline__ float wsum64(float x){
  #pragma unroll
  for (int o = 32; o > 0; o >>= 1) x += __shfl_down(x, o);
  return x;  // valid in lane 0
}

// ---------- kernel A: per-k prep (register GJ, 1 barrier/iter) --------------
// BG is pre-zeroed by hipMemsetAsync; only real entries are written.
__global__ __launch_bounds__(256) void prep_kernel(
    const float* __restrict__ mu_k, const float* __restrict__ Psi,
    const float* __restrict__ nu_a, const float* __restrict__ kap_a,
    f16* __restrict__ BG, float* __restrict__ c0o)
{
  const int k = blockIdx.x;
  const int tid = threadIdx.x;
  const int row = tid & 63;
  const int ch  = tid >> 6;        // column chunk: cols [ch*32, ch*32+32) of 128
  const int c0  = ch << 5;

  __shared__ float pr[2][128];
  __shared__ float fc[2][64];
  __shared__ float diag[64];
  __shared__ float muk[64];
  __shared__ float vpart[2][64];
  __shared__ float Ediag[64];

  float Wr[32];
  if (ch < 2){
    const float* Pg = Psi + (size_t)k * 4096 + (size_t)row * 64 + c0;
    #pragma unroll
    for (int c = 0; c < 32; ++c) Wr[c] = Pg[c];
  } else {
    #pragma unroll
    for (int c = 0; c < 32; ++c) Wr[c] = ((c0 - 64 + c) == row) ? 1.f : 0.f;
  }
  if (tid < 64) muk[tid] = mu_k[k * 64 + tid];
  if (row == 0){
    #pragma unroll
    for (int c = 0; c < 32; ++c) pr[0][c0 + c] = Wr[c];
  }
  if (ch == 0) fc[0][row] = Wr[0];
  __syncthreads();

  for (int jh = 0; jh < 2; ++jh){
    #pragma unroll
    for (int jl = 0; jl < 32; ++jl){
      const int j = jh * 32 + jl;
      const int cur = j & 1, nxt = cur ^ 1;
      float piv = pr[cur][j];
      float f = fc[cur][row] * __builtin_amdgcn_rcpf(piv);
      if (row == j && ch == 0) diag[j] = piv;
      if (row != j){
        #pragma unroll
        for (int c = 0; c < 32; ++c) Wr[c] = fmaf(-f, pr[cur][c0 + c], Wr[c]);
      }
      if (j < 63){
        if (row == j + 1){
          #pragma unroll
          for (int c = 0; c < 32; ++c) pr[nxt][c0 + c] = Wr[c];
        }
        if (jl < 31){ if (ch == jh)     fc[nxt][row] = Wr[jl + 1]; }
        else        { if (ch == jh + 1) fc[nxt][row] = Wr[0]; }
      }
      __syncthreads();
    }
  }

  const float nu = nu_a[k];
  const int j_k = k >> 4, kck = k & 15;

  if (ch >= 2){
    const int h = ch - 2;                   // e-half this thread owns
    const float dinv = nu / diag[row];
    float vp = 0.f;
    #pragma unroll
    for (int c = 0; c < 32; ++c) vp = fmaf(Wr[c], muk[h * 32 + c], vp);
    vpart[h][row] = vp * dinv;
    // E-row scatter into symmetric pair-block layout (only bI <= bJ stored)
    const int d = row;
    const int bI = d >> 3;
    const int pch = (d >> 2) & 1;
    const int sHi = d & 3;                  // g-slot
    #pragma unroll
    for (int cc = 0; cc < 32; ++cc){
      const int e = h * 32 + cc;
      const int bJ = e >> 3;
      float val = Wr[cc] * dinv;
      if (e == d) Ediag[row] = val;
      if (bI <= bJ){
        const int pb = ((bJ * (bJ + 1)) >> 1) + bI;
        const int ci = pb * 2 + pch;
        const float sc = (bI < bJ) ? 2.f : 1.f;
        BG[(size_t)((ci * 3 + j_k) * 64 + kck * 4 + sHi) * 8 + (e & 7)] = (f16)(val * sc);
      }
    }
  }
  __syncthreads();

  if (tid < 64){
    const int t = tid;
    float v = vpart[0][t] + vpart[1][t];
    const int g = (t >> 3) & 3, q = t & 7;
    const int cA = 72 + (t >> 5);
    const int cB = 74 + (t >> 5);
    BG[(size_t)((cA * 3 + j_k) * 64 + kck * 4 + g) * 8 + q] = (f16)(-2.f * v);
    BG[(size_t)((cB * 3 + j_k) * 64 + kck * 4 + g) * 8 + q] = (f16)(Ediag[t]);
    float c2 = wsum64(v * muk[t]);
    float dg = wsum64(digammaf_((nu - (float)t) * 0.5f));
    float ld = wsum64(logf(diag[t]));
    if (t == 0){
      const float LN2   = 0.69314718055994531f;
      const float LN2PI = 1.83787706640934548f;
      float Elogdet = dg + 64.f * LN2 - ld;
      float cst = 0.5f * (Elogdet - 64.f * LN2PI);
      c0o[k] = cst - 0.5f * c2 - 32.f / kap_a[k];
    }
  }
}

// ---- kernel B: main (f16 MFMA, LDS-ring B staging, 8-wave blocks) ----------
#define BUILD(AF, FD2, MUD)                                                \
  {                                                                        \
    float s_[8];                                                           \
    _Pragma("unroll")                                                      \
    for (int q_ = 0; q_ < 8; ++q_) s_[q_] = (MUD) * mue[q_];               \
    _Pragma("unroll")                                                      \
    for (int r_ = 0; r_ < 4; ++r_){                                        \
      _Pragma("unroll")                                                    \
      for (int q_ = 0; q_ < 8; ++q_)                                       \
        s_[q_] = DOT2((FD2).p[r_], FeT2[q_].p[r_], s_[q_]);                \
    }                                                                      \
    _Pragma("unroll")                                                      \
    for (int p_ = 0; p_ < 4; ++p_){                                        \
      h2 pk_ = __builtin_bit_cast(h2,                                      \
          __builtin_amdgcn_cvt_pkrtz(s_[2 * p_], s_[2 * p_ + 1]));         \
      (AF)[2 * p_]     = pk_[0];                                           \
      (AF)[2 * p_ + 1] = pk_[1];                                           \
    }                                                                      \
  }

#define MFMA3(AF, B0, B1, B2)                                              \
  acc0 = __builtin_amdgcn_mfma_f32_16x16x32_f16((AF), (B0), acc0, 0, 0, 0);\
  acc1 = __builtin_amdgcn_mfma_f32_16x16x32_f16((AF), (B1), acc1, 0, 0, 0);\
  acc2 = __builtin_amdgcn_mfma_f32_16x16x32_f16((AF), (B2), acc2, 0, 0, 0);

__global__ __launch_bounds__(512, 2) void main_kernel(
    const float* __restrict__ mu_t, const float* __restrict__ var_t,
    const float* __restrict__ F_t, const unsigned char* __restrict__ maskb,
    const f16* __restrict__ BG, const float* __restrict__ c0o,
    float* __restrict__ out)
{
  __shared__ __align__(16) f16 sG[BT_BLK][64][8];   // F[d][r], d^(bt&7); 32 KB
  __shared__ __align__(16) f16 sMu[BT_BLK][64];     // block-8 d-swizzle;   4 KB
  __shared__ __align__(16) f16 sB[4][2][1536];      // B ring: wp x slot;  24 KB

  const int tid = threadIdx.x;
  const int l = tid & 63;
  const int w = tid >> 6;                // 0..7
  const int wp = w & 3;                  // chunk-group id
  const int wt = w >> 2;                 // bt-tile id (0,1)
  const int g = l >> 4;
  const int kc = l & 15;
  const int bt0 = blockIdx.x * BT_BLK;
  const int btl = (wt << 4) | kc;        // this lane's local A row
  const int btSw = kc & 7;               // (btl & 7) == (kc & 7)

  const bool byteMask =
      __any((maskb[4 * l + 1] | maskb[4 * l + 2] | maskb[4 * l + 3]) != 0);

  // ---- stage F / mu into LDS (coalesced, f32->f16) ----
  {
    const float4* fg = (const float4*)(F_t + (size_t)bt0 * 512);
    #pragma unroll
    for (int ii = 0; ii < 8; ++ii){
      int i = tid + ii * 512;
      float4 f = fg[i];
      int bt = i >> 7, rem = i & 127, d = rem >> 1, rb = (rem & 1) << 2;
      int dsw = d ^ (bt & 7);
      f16x4 ff = { (f16)f.x, (f16)f.y, (f16)f.z, (f16)f.w };
      *(f16x4*)&sG[bt][dsw][rb] = ff;
    }
    const float4* mg = (const float4*)(mu_t + (size_t)bt0 * 64);
    {
      int i = tid;
      float4 m4 = mg[i];
      int bt = i >> 4, d0 = (i & 15) << 2;
      int dsw = (((d0 >> 3) ^ (bt & 7)) << 3) | (d0 & 7);
      f16x4 mm = { (f16)m4.x, (f16)m4.y, (f16)m4.z, (f16)m4.w };
      *(f16x4*)&sMu[bt][dsw] = mm;
    }
  }

  // ---- producer (wt==0): stage chunk list[0] = 18*wp into ring slot 0 ----
  if (wt == 0){
    const f16* src = BG + (size_t)(18 * wp) * 1536 + l * 8;
    f16x8 s0 = *(const f16x8*)(src);
    f16x8 s1 = *(const f16x8*)(src + 512);
    f16x8 s2 = *(const f16x8*)(src + 1024);
    f16* dst = &sB[wp][0][l * 8];
    *(f16x8*)(dst) = s0;
    *(f16x8*)(dst + 512) = s1;
    *(f16x8*)(dst + 1024) = s2;
  }

  // ---- ext-chunk A-fragment (hoisted): wp<2 -> mu slice, wp>=2 -> var ----
  f16x8 afExt;
  if (wp < 2){
    const float* vr = mu_t + (size_t)(bt0 + btl) * 64 + wp * 32 + g * 8;
    f32x4 va = *(const f32x4*)(vr);
    f32x4 vb = *(const f32x4*)(vr + 4);
    #pragma unroll
    for (int r = 0; r < 4; ++r){ afExt[r] = (f16)va[r]; afExt[4 + r] = (f16)vb[r]; }
  } else {
    const float* vr = var_t + (size_t)(bt0 + btl) * 64 + (wp - 2) * 32 + g * 8;
    f32x4 va = *(const f32x4*)(vr);
    f32x4 vb = *(const f32x4*)(vr + 4);
    #pragma unroll
    for (int r = 0; r < 4; ++r){ afExt[r] = (f16)va[r]; afExt[4 + r] = (f16)vb[r]; }
  }
  __syncthreads();   // F/mu staged + ring slot 0 ready

  f32x4 acc0 = {0.f,0.f,0.f,0.f}, acc1 = {0.f,0.f,0.f,0.f}, acc2 = {0.f,0.f,0.f,0.f};

  h2q FeT2[8];       // F rows e = bJ*8+q (reloaded per bJ)
  float mue[8];
  int curBJ = -1;

  const int laneB = (kc * 4 + g) * 8;

  for (int t = 0; t < 19; ++t){
    // ---- consume: B fragments from ring slot t&1 ----
    const f16* bs = &sB[wp][t & 1][laneB];
    f16x8 b0 = *(const f16x8*)(bs);
    f16x8 b1 = *(const f16x8*)(bs + 512);
    f16x8 b2 = *(const f16x8*)(bs + 1024);

    // ---- producer issue-early: global loads for chunk list[t+1] ----
    f16x8 st0, st1, st2;
    const bool produce = (wt == 0) && (t < 18);
    if (produce){
      const int cn = (t + 1 < 18) ? (18 * wp + t + 1) : (72 + wp);
      const f16* src = BG + (size_t)cn * 1536 + l * 8;
      st0 = *(const f16x8*)(src);
      st1 = *(const f16x8*)(src + 512);
      st2 = *(const f16x8*)(src + 1024);
    }

    // ---- A fragment ----
    f16x8 af;
    if (t < 18){
      const int pair = 9 * wp + (t >> 1);
      const int bJ = PB_BJ[pair];
      if (bJ != curBJ){
        curBJ = bJ;
        #pragma unroll
        for (int q = 0; q < 8; ++q){
          f16x8 fv = *(const f16x8*)&sG[btl][((bJ << 3) + q) ^ btSw][0];
          FeT2[q] = __builtin_bit_cast(h2q, fv);
        }
        f16x8 mr = *(const f16x8*)&sMu[btl][((bJ ^ btSw) << 3)];
        #pragma unroll
        for (int q = 0; q < 8; ++q) mue[q] = (float)mr[q];
      }
      const int bI = PB_BI[pair];
      const int d = bI * 8 + (t & 1) * 4 + g;
      f16x8 fv = *(const f16x8*)&sG[btl][(d & 7 ? d : d) ^ btSw][0];  // d ^ btSw on low bits
      h2q fd2 = __builtin_bit_cast(h2q, *(const f16x8*)&sG[btl][d ^ btSw][0]);
      (void)fv;
      float mud = (float)sMu[btl][(((d >> 3) ^ btSw) << 3) | (d & 7)];
      BUILD(af, fd2, mud);
    } else {
      af = afExt;
    }

    MFMA3(af, b0, b1, b2);

    // ---- producer write-late: publish chunk list[t+1] into slot (t+1)&1 ----
    if (produce){
      f16* dst = &sB[wp][(t + 1) & 1][l * 8];
      *(f16x8*)(dst) = st0;
      *(f16x8*)(dst + 512) = st1;
      *(f16x8*)(dst + 1024) = st2;
    }
    __syncthreads();
  }

  // ---- cross-group reduce within each bt-tile (aliased into sG) ----
  float* sRedF = (float*)sG;               // [6][64][13] floats = 19968 B
  if (wp != 0){
    const int bofs = ((wt * 3 + wp - 1) * 64 + l) * 13;
    #pragma unroll
    for (int r = 0; r < 4; ++r){
      sRedF[bofs + r]     = acc0[r];
      sRedF[bofs + 4 + r] = acc1[r];
      sRedF[bofs + 8 + r] = acc2[r];
    }
  }
  __syncthreads();
  if (wp == 0){
    #pragma unroll
    for (int ss = 0; ss < 3; ++ss){
      const int bofs = ((wt * 3 + ss) * 64 + l) * 13;
      #pragma unroll
      for (int r = 0; r < 4; ++r){
        acc0[r] += sRedF[bofs + r];
        acc1[r] += sRedF[bofs + 4 + r];
        acc2[r] += sRedF[bofs + 8 + r];
      }
    }
    float c0a = c0o[kc];
    float c0b = c0o[16 + kc];
    float c0c = c0o[32];
    #pragma unroll
    for (int reg = 0; reg < 4; ++reg){
      int obt = bt0 + wt * 16 + g * 4 + reg;
      bool mk = byteMask ? (maskb[obt] != 0) : (maskb[(size_t)4 * obt] != 0);
      float* op = out + (size_t)obt * 33;
      op[kc]      = mk ? fmaf(-0.5f, acc0[reg], c0a) : 0.f;
      op[16 + kc] = mk ? fmaf(-0.5f, acc1[reg], c0b) : 0.f;
      if (kc == 0) op[32] = mk ? fmaf(-0.5f, acc2[reg], c0c) : 0.f;
    }
  }
}

// --------------------------- launch -----------------------------------------
extern "C" void kernel_launch(void* const* d_in, const int* in_sizes, int n_in,
                              void* d_out, int out_size, void* d_ws, size_t ws_size,
                              hipStream_t stream)
{
  const float* mu_t  = (const float*)d_in[0];
  const float* var_t = (const float*)d_in[1];
  const float* F_t   = (const float*)d_in[2];
  const float* mu_k  = (const float*)d_in[3];
  const float* Psi   = (const float*)d_in[4];
  const float* nu    = (const float*)d_in[5];
  const float* kap   = (const float*)d_in[6];
  const unsigned char* mask = (const unsigned char*)d_in[7];

  f16*   BG  = (f16*)d_ws;                      // 76*3*64*8 f16 = 233472 B
  float* c0o = (float*)((char*)d_ws + (size_t)NCHUNK * 3 * 64 * 8 * 2);
  float* outp = (float*)d_out;

  (void)hipMemsetAsync(d_ws, 0, (size_t)NCHUNK * 3 * 64 * 8 * 2, stream);
  hipLaunchKernelGGL(prep_kernel, dim3(33), dim3(256), 0, stream,
                     mu_k, Psi, nu, kap, BG, c0o);
  hipLaunchKernelGGL(main_kernel, dim3(BT_TOTAL / BT_BLK), dim3(512), 0, stream,
                     mu_t, var_t, F_t, mask, BG, c0o, outp);
}

// Round 18
// 76.617 us; speedup vs baseline: 1.2012x; 1.2012x over previous
//
#include <hip/hip_runtime.h>

// ---------------------------------------------------------------------------
// StickyHDPHMMVI emission log-likelihood, f16 MFMA + symmetry formulation:
// out[bt,k] = c0_k - 0.5 * sum_x A[bt,x] * B[k,x]
// x enumerates SYMMETRIC pair-blocks (bI<=bJ) of the 64x64 (d,e) space:
//   pair pb=(bI,bJ), chunks c = pb*2+p (p=0,1), slot s = g*8+q:
//     d = bI*8 + p*4 + g, e = bJ*8 + q
//     A = S0[d][e] (mu muT + F FT),  B = E_k[d][e] * (bI<bJ ? 2 : 1)
//   c=72,73: A = mu[t],  B = -2*v_k[t];  c=74,75: A = var[t], B = E_k[t,t]
// B lane-ordered: BG[((c*3 + j)*64 + kc*4 + g)*8 + q], k = j*16+kc
// r19 (base = r10, the 80.3us best): k-columns 0..31 via TWO MFMA (j=0,1);
// k=32 via per-lane 4x v_dot2 against the (j=2,kc=0) B-row (16B L1 load) +
// shfl_xor g-reduce. Third MFMA (15/16 wasted) eliminated; prep drops the
// k>=33 zero-fill blocks (those rows are never read now) -> grid 33, no
// memset. Ext chunks absolute (r9). Natural reg footprint, no min-wave cap
// (r11). Refuted-null pile: addressing(r13), reg budget(r15), L1 pair(r16),
// LDS ring(r17).
// ---------------------------------------------------------------------------

#define BT_TOTAL 32768
#define BT_BLK 16
#define NCHUNK 76

typedef _Float16 f16;
typedef __attribute__((ext_vector_type(8))) _Float16 f16x8;
typedef __attribute__((ext_vector_type(4))) _Float16 f16x4;
typedef __attribute__((ext_vector_type(2))) _Float16 h2;
typedef __attribute__((ext_vector_type(4))) float f32x4;
typedef struct { h2 p[4]; } h2q;

#if __has_builtin(__builtin_amdgcn_fdot2)
#define DOT2(a, b, c) __builtin_amdgcn_fdot2((a), (b), (c), false)
#else
#define DOT2(a, b, c) fmaf((float)(a)[0], (float)(b)[0], fmaf((float)(a)[1], (float)(b)[1], (c)))
#endif

// pair-block tables (bJ outer 0..7, bI inner 0..bJ), +1 guard entry
__constant__ unsigned char PB_BJ[37] =
  {0, 1,1, 2,2,2, 3,3,3,3, 4,4,4,4,4, 5,5,5,5,5,5, 6,6,6,6,6,6,6, 7,7,7,7,7,7,7,7, 7};
__constant__ unsigned char PB_BI[37] =
  {0, 0,1, 0,1,2, 0,1,2,3, 0,1,2,3,4, 0,1,2,3,4,5, 0,1,2,3,4,5,6, 0,1,2,3,4,5,6,7, 7};

__device__ __forceinline__ float digammaf_(float x){
  float r = 0.f;
  while (x < 6.f){ r -= 1.f / x; x += 1.f; }
  float xi = 1.f / x;
  float xi2 = xi * xi;
  return r + logf(x) - 0.5f * xi
         - xi2 * (0.083333333333f - xi2 * (0.0083333333333f - xi2 * 0.0039682539683f));
}

__device__ __forceinline__ float wsum64(float x){
  #pragma unroll
  for (int o = 32; o > 0; o >>= 1) x += __shfl_down(x, o);
  return x;  // valid in lane 0
}

// ---------- kernel A: per-k prep (register GJ, 1 barrier/iter) --------------
// Only k=0..32 launched; j=2 rows with kck>=1 are never read by main.
__global__ __launch_bounds__(256) void prep_kernel(
    const float* __restrict__ mu_k, const float* __restrict__ Psi,
    const float* __restrict__ nu_a, const float* __restrict__ kap_a,
    f16* __restrict__ BG, float* __restrict__ c0o)
{
  const int k = blockIdx.x;
  const int tid = threadIdx.x;
  const int row = tid & 63;
  const int ch  = tid >> 6;        // column chunk: cols [ch*32, ch*32+32) of 128
  const int c0  = ch << 5;

  __shared__ float pr[2][128];
  __shared__ float fc[2][64];
  __shared__ float diag[64];
  __shared__ float muk[64];
  __shared__ float vpart[2][64];
  __shared__ float Ediag[64];

  float Wr[32];
  if (ch < 2){
    const float* Pg = Psi + (size_t)k * 4096 + (size_t)row * 64 + c0;
    #pragma unroll
    for (int c = 0; c < 32; ++c) Wr[c] = Pg[c];
  } else {
    #pragma unroll
    for (int c = 0; c < 32; ++c) Wr[c] = ((c0 - 64 + c) == row) ? 1.f : 0.f;
  }
  if (tid < 64) muk[tid] = mu_k[k * 64 + tid];
  if (row == 0){
    #pragma unroll
    for (int c = 0; c < 32; ++c) pr[0][c0 + c] = Wr[c];
  }
  if (ch == 0) fc[0][row] = Wr[0];
  __syncthreads();

  for (int jh = 0; jh < 2; ++jh){
    #pragma unroll
    for (int jl = 0; jl < 32; ++jl){
      const int j = jh * 32 + jl;
      const int cur = j & 1, nxt = cur ^ 1;
      float piv = pr[cur][j];
      float f = fc[cur][row] * __builtin_amdgcn_rcpf(piv);
      if (row == j && ch == 0) diag[j] = piv;
      if (row != j){
        #pragma unroll
        for (int c = 0; c < 32; ++c) Wr[c] = fmaf(-f, pr[cur][c0 + c], Wr[c]);
      }
      if (j < 63){
        if (row == j + 1){
          #pragma unroll
          for (int c = 0; c < 32; ++c) pr[nxt][c0 + c] = Wr[c];
        }
        if (jl < 31){ if (ch == jh)     fc[nxt][row] = Wr[jl + 1]; }
        else        { if (ch == jh + 1) fc[nxt][row] = Wr[0]; }
      }
      __syncthreads();
    }
  }

  const float nu = nu_a[k];
  const int j_k = k >> 4, kck = k & 15;

  if (ch >= 2){
    const int h = ch - 2;                   // e-half this thread owns
    const float dinv = nu / diag[row];
    float vp = 0.f;
    #pragma unroll
    for (int c = 0; c < 32; ++c) vp = fmaf(Wr[c], muk[h * 32 + c], vp);
    vpart[h][row] = vp * dinv;
    // E-row scatter into symmetric pair-block layout (only bI <= bJ stored)
    const int d = row;
    const int bI = d >> 3;
    const int pch = (d >> 2) & 1;
    const int sHi = d & 3;                  // g-slot
    #pragma unroll
    for (int cc = 0; cc < 32; ++cc){
      const int e = h * 32 + cc;
      const int bJ = e >> 3;
      float val = Wr[cc] * dinv;
      if (e == d) Ediag[row] = val;
      if (bI <= bJ){
        const int pb = ((bJ * (bJ + 1)) >> 1) + bI;
        const int ci = pb * 2 + pch;
        const float sc = (bI < bJ) ? 2.f : 1.f;
        BG[(size_t)((ci * 3 + j_k) * 64 + kck * 4 + sHi) * 8 + (e & 7)] = (f16)(val * sc);
      }
    }
  }
  __syncthreads();

  if (tid < 64){
    const int t = tid;
    float v = vpart[0][t] + vpart[1][t];
    const int g = (t >> 3) & 3, q = t & 7;
    const int cA = 72 + (t >> 5);
    const int cB = 74 + (t >> 5);
    BG[(size_t)((cA * 3 + j_k) * 64 + kck * 4 + g) * 8 + q] = (f16)(-2.f * v);
    BG[(size_t)((cB * 3 + j_k) * 64 + kck * 4 + g) * 8 + q] = (f16)(Ediag[t]);
    float c2 = wsum64(v * muk[t]);
    float dg = wsum64(digammaf_((nu - (float)t) * 0.5f));
    float ld = wsum64(logf(diag[t]));
    if (t == 0){
      const float LN2   = 0.69314718055994531f;
      const float LN2PI = 1.83787706640934548f;
      float Elogdet = dg + 64.f * LN2 - ld;
      float cst = 0.5f * (Elogdet - 64.f * LN2PI);
      c0o[k] = cst - 0.5f * c2 - 32.f / kap_a[k];
    }
  }
}

// -------- kernel B: main (f16 MFMA x2 + k32 dot, 128-thr blocks) ------------
#define BUILD(AF, FD, MUD)                                                 \
  {                                                                        \
    float s_[8];                                                           \
    _Pragma("unroll")                                                      \
    for (int q_ = 0; q_ < 8; ++q_) s_[q_] = (MUD) * mue[q_];               \
    _Pragma("unroll")                                                      \
    for (int r_ = 0; r_ < 4; ++r_){                                        \
      h2 fp_ = { (FD)[2 * r_], (FD)[2 * r_ + 1] };                         \
      _Pragma("unroll")                                                    \
      for (int q_ = 0; q_ < 8; ++q_){                                      \
        h2 ep_ = { FeT[q_][2 * r_], FeT[q_][2 * r_ + 1] };                 \
        s_[q_] = DOT2(fp_, ep_, s_[q_]);                                   \
      }                                                                    \
    }                                                                      \
    _Pragma("unroll")                                                      \
    for (int q_ = 0; q_ < 8; ++q_) (AF)[q_] = (f16)s_[q_];                 \
  }

#define MFMA2(AF, B0, B1)                                                  \
  acc0 = __builtin_amdgcn_mfma_f32_16x16x32_f16((AF), (B0), acc0, 0, 0, 0);\
  acc1 = __builtin_amdgcn_mfma_f32_16x16x32_f16((AF), (B1), acc1, 0, 0, 0);

#define K32DOT(AF, B32)                                                    \
  {                                                                        \
    h2q afq_ = __builtin_bit_cast(h2q, (AF));                              \
    h2q bq_  = __builtin_bit_cast(h2q, (B32));                             \
    _Pragma("unroll")                                                      \
    for (int r_ = 0; r_ < 4; ++r_)                                         \
      acc32 = DOT2(afq_.p[r_], bq_.p[r_], acc32);                          \
  }

__global__ __launch_bounds__(128) void main_kernel(
    const float* __restrict__ mu_t, const float* __restrict__ var_t,
    const float* __restrict__ F_t, const unsigned char* __restrict__ maskb,
    const f16* __restrict__ BG, const float* __restrict__ c0o,
    float* __restrict__ out)
{
  __shared__ __align__(16) f16 sG[BT_BLK][64][8];  // F[d][r], d^(bt&7); 16384 B
  __shared__ __align__(16) f16 sMu[BT_BLK][64];    // block-8 d-swizzle;  2048 B

  const int tid = threadIdx.x;
  const int l = tid & 63;
  const int xh = tid >> 6;               // wave = pair-range half
  const int g = l >> 4;
  const int kc = l & 15;
  const int bt0 = blockIdx.x * BT_BLK;
  const int btl = kc;                    // this lane's local A row
  const int btSw = btl & 7;

  const bool byteMask =
      __any((maskb[4 * l + 1] | maskb[4 * l + 2] | maskb[4 * l + 3]) != 0);

  // ---- stage F / mu into LDS (coalesced, f32->f16) ----
  {
    const float4* fg = (const float4*)(F_t + (size_t)bt0 * 512);
    #pragma unroll
    for (int ii = 0; ii < 16; ++ii){
      int i = tid + ii * 128;
      float4 f = fg[i];
      int bt = i >> 7, rem = i & 127, d = rem >> 1, rb = (rem & 1) << 2;
      int dsw = d ^ (bt & 7);
      f16x4 ff = { (f16)f.x, (f16)f.y, (f16)f.z, (f16)f.w };
      *(f16x4*)&sG[bt][dsw][rb] = ff;
    }
    const float4* mg = (const float4*)(mu_t + (size_t)bt0 * 64);
    #pragma unroll
    for (int ii = 0; ii < 2; ++ii){
      int i = tid + ii * 128;
      float4 m4 = mg[i];
      int bt = i >> 4, d0 = (i & 15) << 2;
      int dsw = (((d0 >> 3) ^ (bt & 7)) << 3) | (d0 & 7);
      f16x4 mm = { (f16)m4.x, (f16)m4.y, (f16)m4.z, (f16)m4.w };
      *(f16x4*)&sMu[bt][dsw] = mm;
    }
  }
  __syncthreads();

  // per-wave pair range: wave0 = pairs [0,19), wave1 = pairs [19,36) + ext
  const int ppStart = xh ? 19 : 0;
  const int ppEnd   = xh ? 36 : 19;

  f32x4 acc0 = {0.f,0.f,0.f,0.f}, acc1 = {0.f,0.f,0.f,0.f};
  float acc32 = 0.f;

  f16x8 FeT[8];      // F rows e = bJ*8+q (reloaded per bJ)
  float mue[8];

  const f16* bp   = BG + (size_t)(ppStart * 2) * 1536 + (size_t)(kc * 4 + g) * 8;
  const f16* bp32 = BG + (size_t)(ppStart * 2) * 1536 + 1024 + (size_t)g * 8;

  // prologue: stage A = chunk 2*ppStart, stage B = chunk 2*ppStart+1
  const int bI0 = PB_BI[ppStart];
  f16x8 fdA = *(const f16x8*)&sG[btl][(bI0 * 8 + g) ^ btSw][0];
  f16x8 fdB = *(const f16x8*)&sG[btl][(bI0 * 8 + 4 + g) ^ btSw][0];
  float mudA = (float)sMu[btl][((bI0 ^ btSw) << 3) | g];
  float mudB = (float)sMu[btl][((bI0 ^ btSw) << 3) | (4 + g)];

  f16x8 a0 = *(const f16x8*)(bp);
  f16x8 a1 = *(const f16x8*)(bp + 512);
  f16x8 b0v = *(const f16x8*)(bp + 1536);
  f16x8 b1v = *(const f16x8*)(bp + 1536 + 512);
  f16x8 w0v = *(const f16x8*)(bp32);
  f16x8 w1v = *(const f16x8*)(bp32 + 1536);
  bp += 3072;
  bp32 += 3072;

  int curBJ = -1;
  for (int pp = ppStart; pp < ppEnd; ++pp){
    const int bJ = PB_BJ[pp];
    if (bJ != curBJ){
      curBJ = bJ;
      #pragma unroll
      for (int q = 0; q < 8; ++q)
        FeT[q] = *(const f16x8*)&sG[btl][((bJ << 3) + q) ^ btSw][0];
      f16x8 mr = *(const f16x8*)&sMu[btl][((bJ ^ btSw) << 3)];
      #pragma unroll
      for (int q = 0; q < 8; ++q) mue[q] = (float)mr[q];
    }
    const int bIn = PB_BI[pp + 1];
    // ---- even chunk (stage A), refill with next pair's p=0 ----
    {
      f16x8 af;
      BUILD(af, fdA, mudA);
      MFMA2(af, a0, a1);
      K32DOT(af, w0v);
      a0 = *(const f16x8*)(bp);
      a1 = *(const f16x8*)(bp + 512);
      w0v = *(const f16x8*)(bp32);
      fdA = *(const f16x8*)&sG[btl][(bIn * 8 + g) ^ btSw][0];
      mudA = (float)sMu[btl][((bIn ^ btSw) << 3) | g];
    }
    // ---- odd chunk (stage B), refill with next pair's p=1 ----
    {
      f16x8 af;
      BUILD(af, fdB, mudB);
      MFMA2(af, b0v, b1v);
      K32DOT(af, w1v);
      b0v = *(const f16x8*)(bp + 1536);
      b1v = *(const f16x8*)(bp + 1536 + 512);
      w1v = *(const f16x8*)(bp32 + 1536);
      fdB = *(const f16x8*)&sG[btl][(bIn * 8 + 4 + g) ^ btSw][0];
      mudB = (float)sMu[btl][((bIn ^ btSw) << 3) | (4 + g)];
    }
    bp += 3072;
    bp32 += 3072;
  }

  // ---- ext chunks (wave 1 only), ABSOLUTE addressing at chunk 72 ----
  if (xh == 1){
    const f16* bpe   = BG + (size_t)72 * 1536 + (size_t)(kc * 4 + g) * 8;
    const f16* bpe32 = BG + (size_t)72 * 1536 + 1024 + (size_t)g * 8;
    #pragma unroll
    for (int m = 0; m < 4; ++m){
      f16x8 af;
      if (m < 2){
        af = *(const f16x8*)&sMu[btl][(((m * 4 + g) ^ btSw) << 3)];
      } else {
        const float* vr = var_t + (size_t)(bt0 + btl) * 64 + (m - 2) * 32 + g * 8;
        f32x4 va = *(const f32x4*)(vr);
        f32x4 vb = *(const f32x4*)(vr + 4);
        #pragma unroll
        for (int r = 0; r < 4; ++r){ af[r] = (f16)va[r]; af[4 + r] = (f16)vb[r]; }
      }
      f16x8 e0 = *(const f16x8*)(bpe);
      f16x8 e1 = *(const f16x8*)(bpe + 512);
      f16x8 e32 = *(const f16x8*)(bpe32);
      MFMA2(af, e0, e1);
      K32DOT(af, e32);
      bpe += 1536;
      bpe32 += 1536;
    }
  }

  // ---- cross-wave reduce (aliased into sG after barrier) ----
  __syncthreads();                         // all waves done reading sG/sMu
  float* sRedF = (float*)sG;               // [64][9] floats = 2304 B
  if (xh == 1){
    const int bofs = l * 9;
    #pragma unroll
    for (int r = 0; r < 4; ++r){
      sRedF[bofs + r]     = acc0[r];
      sRedF[bofs + 4 + r] = acc1[r];
    }
    sRedF[bofs + 8] = acc32;
  }
  __syncthreads();
  if (xh == 0){
    const int bofs = l * 9;
    #pragma unroll
    for (int r = 0; r < 4; ++r){
      acc0[r] += sRedF[bofs + r];
      acc1[r] += sRedF[bofs + 4 + r];
    }
    acc32 += sRedF[bofs + 8];
    // g-reduce k32 (lanes same kc, different g)
    acc32 += __shfl_xor(acc32, 16);
    acc32 += __shfl_xor(acc32, 32);

    float c0a = c0o[kc];
    float c0b = c0o[16 + kc];
    float c0c = c0o[32];
    #pragma unroll
    for (int reg = 0; reg < 4; ++reg){
      int obt = bt0 + g * 4 + reg;
      bool mk = byteMask ? (maskb[obt] != 0) : (maskb[(size_t)4 * obt] != 0);
      float* op = out + (size_t)obt * 33;
      op[kc]      = mk ? fmaf(-0.5f, acc0[reg], c0a) : 0.f;
      op[16 + kc] = mk ? fmaf(-0.5f, acc1[reg], c0b) : 0.f;
    }
    if (g == 0){
      int obt2 = bt0 + kc;
      bool mk2 = byteMask ? (maskb[obt2] != 0) : (maskb[(size_t)4 * obt2] != 0);
      out[(size_t)obt2 * 33 + 32] = mk2 ? fmaf(-0.5f, acc32, c0c) : 0.f;
    }
  }
}

// --------------------------- launch -----------------------------------------
extern "C" void kernel_launch(void* const* d_in, const int* in_sizes, int n_in,
                              void* d_out, int out_size, void* d_ws, size_t ws_size,
                              hipStream_t stream)
{
  const float* mu_t  = (const float*)d_in[0];
  const float* var_t = (const float*)d_in[1];
  const float* F_t   = (const float*)d_in[2];
  const float* mu_k  = (const float*)d_in[3];
  const float* Psi   = (const float*)d_in[4];
  const float* nu    = (const float*)d_in[5];
  const float* kap   = (const float*)d_in[6];
  const unsigned char* mask = (const unsigned char*)d_in[7];

  f16*   BG  = (f16*)d_ws;                      // 76*3*64*8 f16 = 233472 B
  float* c0o = (float*)((char*)d_ws + (size_t)NCHUNK * 3 * 64 * 8 * 2);
  float* outp = (float*)d_out;

  hipLaunchKernelGGL(prep_kernel, dim3(33), dim3(256), 0, stream,
                     mu_k, Psi, nu, kap, BG, c0o);
  hipLaunchKernelGGL(main_kernel, dim3(BT_TOTAL / BT_BLK), dim3(128), 0, stream,
                     mu_t, var_t, F_t, mask, BG, c0o, outp);
}